// Round 7
// baseline (391.636 us; speedup 1.0000x reference)
//
#include <hip/hip_runtime.h>
#include <cfloat>

// Geometry: z (32,256,32,32) f32, W (1024,256) f32.
// P = 32768 (p = n*1024+hw), K = 256, CODES = 1024.
// d_out = [quantized 8388608][straight_through 8388608][indices-as-float 32768]
// Strategy: bf16 MFMA screen (candidates within EPS of min) + exact fp32
// rescore (bitwise-identical chain). Rescore stages z coalesced via LDS and
// computes zsq inline (numpy pairwise order) — no uncoalesced z reads left.

#define P_TOTAL   32768
#define N_CODES   1024
#define Q_ELEMS   8388608
#define EPS_SCREEN 1.0e-2f   // rigorous bf16-screen bound is ~2.3e-3; 4x margin
#define CAND_CAP  64

typedef __attribute__((ext_vector_type(8))) short bf16x8;
typedef __attribute__((ext_vector_type(4))) float f32x4;

#define GLOAD16(gsrc, ldst) \
  __builtin_amdgcn_global_load_lds((const __attribute__((address_space(1))) void*)(gsrc), \
                                   (__attribute__((address_space(3))) void*)(ldst), 16, 0, 0)

__device__ __forceinline__ unsigned short f2bf(float f) {   // RN-even f32->bf16
    unsigned u = __builtin_bit_cast(unsigned, f);
    u += 0x7FFF + ((u >> 16) & 1);
    return (unsigned short)(u >> 16);
}

__device__ __forceinline__ float sq_sep(float v) {
    float t = v * v;
    asm volatile("" : "+v"(t));
    return t;
}

// ---------------------------------------------------------------------------
// k0w: W[1024][256] f32 -> W_hi bf16; 16B granules XOR-swizzled in each 512B
// row: granule g of code c stored at slot g^(c&7).
// ---------------------------------------------------------------------------
__global__ void k0w_pack(const float* __restrict__ wemb, unsigned short* __restrict__ whi) {
    const int t = blockIdx.x * 256 + threadIdx.x;   // 32768 granules
    const int c = t >> 5, g = t & 31;
    const float4 v0 = *(const float4*)&wemb[(size_t)c * 256 + g * 8];
    const float4 v1 = *(const float4*)&wemb[(size_t)c * 256 + g * 8 + 4];
    bf16x8 hv;
    hv[0] = (short)f2bf(v0.x); hv[1] = (short)f2bf(v0.y);
    hv[2] = (short)f2bf(v0.z); hv[3] = (short)f2bf(v0.w);
    hv[4] = (short)f2bf(v1.x); hv[5] = (short)f2bf(v1.y);
    hv[6] = (short)f2bf(v1.z); hv[7] = (short)f2bf(v1.w);
    const int gs = g ^ (c & 7);
    *(bf16x8*)(whi + (size_t)c * 256 + gs * 8) = hv;
}

// ---------------------------------------------------------------------------
// k0z: z [n][k][hw] f32 -> z_hi [p][k] bf16 (transpose via LDS). grid 512.
// ---------------------------------------------------------------------------
#define T16S 280   // ushort stride: 560B rows (16B aligned)
__global__ void k0z_pack(const float* __restrict__ z, unsigned short* __restrict__ zhi) {
    __shared__ unsigned short t16[64 * T16S];   // 35,840 B
    const int tid = threadIdx.x;
    const int n = blockIdx.x >> 4, hc = blockIdx.x & 15;
    const int hw0 = hc * 64;
    const int w = tid >> 6, hl = tid & 63;
    #pragma unroll
    for (int i = 0; i < 64; ++i) {
        const int k = i * 4 + w;
        const float v = z[((size_t)(n * 256 + k) << 10) + hw0 + hl];
        t16[hl * T16S + k] = f2bf(v);
    }
    __syncthreads();
    const int row = tid >> 2, cp = tid & 3;
    const size_t p0 = (size_t)(n * 1024 + hw0);
    #pragma unroll
    for (int i = 0; i < 8; ++i) {
        const int chunk = i * 4 + cp;
        *(bf16x8*)(zhi + (p0 + row) * 256 + chunk * 8) =
            *(const bf16x8*)&t16[row * T16S + chunk * 8];
    }
}

// ---------------------------------------------------------------------------
// k1: wsq[c] only (zsq now computed inside k2r from its LDS-staged z rows).
// numpy pairwise order (128+128, 8 accumulators) — identical to validated R6.
// ---------------------------------------------------------------------------
__global__ void k1_wsq(const float* __restrict__ wemb, float* __restrict__ wsq) {
    const int c = blockIdx.x * 256 + threadIdx.x;
    const float* base = wemb + (size_t)c * 256;
    float half[2];
    #pragma unroll
    for (int h = 0; h < 2; ++h) {
        const float* x = base + h * 128;
        float r[8];
        #pragma unroll
        for (int j = 0; j < 8; ++j) r[j] = sq_sep(x[j]);
        for (int i = 8; i < 128; i += 8) {
            #pragma unroll
            for (int j = 0; j < 8; ++j) r[j] += sq_sep(x[i + j]);
        }
        half[h] = ((r[0] + r[1]) + (r[2] + r[3])) + ((r[4] + r[5]) + (r[6] + r[7]));
    }
    wsq[c] = half[0] + half[1];
}

// ---------------------------------------------------------------------------
// k2s: bf16 MFMA screen. Block = 64 pos (4 waves x 16), grid 512.
// UNCHANGED from validated R5/R6.
// ---------------------------------------------------------------------------
__launch_bounds__(256, 1)
__global__ void k2s_screen(const unsigned short* __restrict__ zhi,
                           const unsigned short* __restrict__ whi,
                           const float* __restrict__ wsq,
                           unsigned short* __restrict__ candC,
                           int* __restrict__ candCnt) {
    __shared__ unsigned short Bs[2][32 * 256];   // 16 KB x2
    __shared__ int cnt[64];
    const int tid = threadIdx.x, bid = blockIdx.x;
    const int w = tid >> 6, l = tid & 63;
    const int la = l & 15, kg = l >> 4;
    const int m0 = bid * 64 + w * 16;
    if (tid < 64) cnt[tid] = 0;

    bf16x8 af[8];
    #pragma unroll
    for (int ks = 0; ks < 8; ++ks)
        af[ks] = *(const bf16x8*)(zhi + (size_t)(m0 + la) * 256 + ks * 32 + kg * 8);

    float rg[4];
    #pragma unroll
    for (int r = 0; r < 4; ++r) rg[r] = FLT_MAX;

#define STAGEB(buf, cb_) do {                                                  \
    const unsigned short* src_ = whi + (size_t)(cb_) * 256;                    \
    _Pragma("unroll")                                                          \
    for (int i_ = 0; i_ < 4; ++i_)                                             \
        GLOAD16(src_ + i_ * 2048 + tid * 8, &Bs[buf][i_ * 2048 + tid * 8]);    \
} while (0)

    STAGEB(0, 0);
    __syncthreads();                      // cnt ready + Bs[0] landed

    for (int ch = 0; ch < 32; ++ch) {
        const int cur = ch & 1;
        const int cb = ch * 32;
        if (ch < 31) STAGEB(cur ^ 1, cb + 32);

        float wsqv[2];
        #pragma unroll
        for (int nf = 0; nf < 2; ++nf) wsqv[nf] = wsq[cb + nf * 16 + la];

        f32x4 acc[2];
        #pragma unroll
        for (int nf = 0; nf < 2; ++nf) acc[nf] = (f32x4){0.f, 0.f, 0.f, 0.f};

        #pragma unroll
        for (int ks = 0; ks < 8; ++ks) {
            bf16x8 bfv[2];
            #pragma unroll
            for (int nf = 0; nf < 2; ++nf) {
                const int cl = nf * 16 + la;
                const int slot = (ks * 4 + kg) ^ (cl & 7);   // un-swizzle
                bfv[nf] = *(const bf16x8*)&Bs[cur][cl * 256 + slot * 8];
            }
            #pragma unroll
            for (int nf = 0; nf < 2; ++nf)
                acc[nf] = __builtin_amdgcn_mfma_f32_16x16x32_bf16(
                    af[ks], bfv[nf], acc[nf], 0, 0, 0);
        }

        float da[2][4];
        #pragma unroll
        for (int nf = 0; nf < 2; ++nf)
            #pragma unroll
            for (int r = 0; r < 4; ++r)
                da[nf][r] = __builtin_fmaf(-2.f, acc[nf][r], wsqv[nf]);

        #pragma unroll
        for (int r = 0; r < 4; ++r) {
            float mv = fminf(da[0][r], da[1][r]);
            #pragma unroll
            for (int off = 1; off < 16; off <<= 1)
                mv = fminf(mv, __shfl_xor(mv, off));
            rg[r] = fminf(rg[r], mv);
        }

        #pragma unroll
        for (int nf = 0; nf < 2; ++nf)
            #pragma unroll
            for (int r = 0; r < 4; ++r)
                if (da[nf][r] <= rg[r] + EPS_SCREEN) {
                    const int plocal = w * 16 + kg * 4 + r;
                    const int slot = atomicAdd(&cnt[plocal], 1);
                    if (slot < CAND_CAP)
                        candC[(size_t)(bid * 64 + plocal) * CAND_CAP + slot] =
                            (unsigned short)(cb + nf * 16 + la);
                }

        __syncthreads();   // Bs[cur] reads done; Bs[cur^1] landed (vmcnt(0))
    }
#undef STAGEB

    if (tid < 64) candCnt[bid * 64 + tid] = cnt[tid];   // raw (overflow detectable)
}

// ---------------------------------------------------------------------------
// k2r: exact rescore, block = 64 positions. Stage the block's z tile
// [64 hw][256 k] fp32 into LDS with COALESCED 256B global reads (the k0z
// pattern) and XOR-swizzled writes (2-way, free). Rescore reads are
// same-address broadcasts (conflict-free).
// zsq computed inline per position with the exact numpy pairwise order
// (identical fp32 values & order => bitwise-identical to validated k1).
// Candidate dots: k-ascending fp32 fma chain, d = fma(-2,dot,zsq)+wsq,
// lex-min (d,c); count>CAP -> full 1024-code sweep. All bitwise-identical
// to the validated R6 rescore.
// ---------------------------------------------------------------------------
__launch_bounds__(256, 2)
__global__ void k2r_rescore(const float* __restrict__ z, const float* __restrict__ wemb,
                            const float* __restrict__ wsq,
                            const unsigned short* __restrict__ candC,
                            const int* __restrict__ candCnt,
                            float* __restrict__ idx_out) {
    __shared__ float t32[64 * 256];   // 64 KB
    const int tid = threadIdx.x;
    const int wv = tid >> 6, l = tid & 63;
    const int p0 = blockIdx.x * 64;
    const int n = p0 >> 10, hw0 = p0 & 1023;

    // coalesced staging: iteration (i,wv) reads k-row k=i*4+wv, lanes span hw
    for (int i = 0; i < 64; ++i) {
        const int k = i * 4 + wv;
        const float v = z[((size_t)(n * 256 + k) << 10) + hw0 + l];
        t32[l * 256 + (k ^ (l & 31))] = v;   // bank = (k^(l&31))&31: 2-way, free
    }
    __syncthreads();

    // each wave rescores 16 positions
    for (int s = 0; s < 16; ++s) {
        const int lp = wv * 16 + s;
        const int p = p0 + lp;
        const float* zrow = &t32[lp * 256];
        const int xm = lp & 31;

        // zsq: numpy pairwise 128+128, 8 accumulators (exact k1 order/values)
        float halfv[2];
        #pragma unroll
        for (int h = 0; h < 2; ++h) {
            float r[8];
            #pragma unroll
            for (int j = 0; j < 8; ++j) r[j] = sq_sep(zrow[(h * 128 + j) ^ xm]);
            for (int i = 8; i < 128; i += 8) {
                #pragma unroll
                for (int j = 0; j < 8; ++j) r[j] += sq_sep(zrow[(h * 128 + i + j) ^ xm]);
            }
            halfv[h] = ((r[0] + r[1]) + (r[2] + r[3])) + ((r[4] + r[5]) + (r[6] + r[7]));
        }
        const float zsv = halfv[0] + halfv[1];

        const int count = candCnt[p];
        float bd = FLT_MAX;
        int bc = N_CODES;
        if (count <= CAND_CAP) {
            if (l < count) {
                const int c = candC[(size_t)p * CAND_CAP + l];
                const float* wb = wemb + (size_t)c * 256;
                float dot = 0.f;
                #pragma unroll 8
                for (int k = 0; k < 256; ++k)
                    dot = __builtin_fmaf(zrow[k ^ xm], wb[k], dot);
                bd = __builtin_fmaf(-2.f, dot, zsv) + wsq[c];
                bc = c;
            }
        } else {
            for (int r = 0; r < 16; ++r) {
                const int c = r * 64 + l;
                const float* wb = wemb + (size_t)c * 256;
                float dot = 0.f;
                #pragma unroll 8
                for (int k = 0; k < 256; ++k)
                    dot = __builtin_fmaf(zrow[k ^ xm], wb[k], dot);
                const float d = __builtin_fmaf(-2.f, dot, zsv) + wsq[c];
                if (d < bd || (d == bd && c < bc)) { bd = d; bc = c; }
            }
        }

        // lex-min (d, c) across the 64 lanes
        #pragma unroll
        for (int off = 1; off < 64; off <<= 1) {
            const float od = __shfl_xor(bd, off);
            const int   oi = __shfl_xor(bc, off);
            if (od < bd || (od == bd && oi < bc)) { bd = od; bc = oi; }
        }
        if (l == 0) idx_out[p] = (float)bc;
    }
}

// ---------------------------------------------------------------------------
// k3: gather + straight-through, NCHW float4 writes
// ---------------------------------------------------------------------------
__global__ void k3_gather(const float* __restrict__ z, const float* __restrict__ wemb,
                          const float* __restrict__ idxf,
                          float* __restrict__ out0, float* __restrict__ out1) {
    const int t = blockIdx.x * 256 + threadIdx.x;
    const int hw4 = t & 255, c = (t >> 8) & 255, n = t >> 16;
    const size_t zo = (((size_t)(n * 256 + c)) << 10) + hw4 * 4;
    const float4 zv = *(const float4*)&z[zo];
    const float4 iv = *(const float4*)&idxf[n * 1024 + hw4 * 4];
    float4 qv, st;
    {
        const int i0 = (int)iv.x; qv.x = wemb[(size_t)i0 * 256 + c]; st.x = (qv.x - zv.x) + zv.x;
        const int i1 = (int)iv.y; qv.y = wemb[(size_t)i1 * 256 + c]; st.y = (qv.y - zv.y) + zv.y;
        const int i2 = (int)iv.z; qv.z = wemb[(size_t)i2 * 256 + c]; st.z = (qv.z - zv.z) + zv.z;
        const int i3 = (int)iv.w; qv.w = wemb[(size_t)i3 * 256 + c]; st.w = (qv.w - zv.w) + zv.w;
    }
    *(float4*)&out0[zo] = qv;
    *(float4*)&out1[zo] = st;
}

extern "C" void kernel_launch(void* const* d_in, const int* in_sizes, int n_in,
                              void* d_out, int out_size, void* d_ws, size_t ws_size,
                              hipStream_t stream) {
    const float* z = (const float*)d_in[0];
    const float* wemb = (const float*)d_in[1];
    float* out = (float*)d_out;
    float* out0 = out;                       // quantized (final)
    float* out1 = out + Q_ELEMS;             // straight_through (final)
    float* oidx = out + 2 * Q_ELEMS;         // indices-as-float (final)
    // big scratch inside d_out (all consumed before k3 overwrites):
    unsigned short* zhi = (unsigned short*)out0;                  // 16 MB
    unsigned short* candC = (unsigned short*)(out0 + 4194304);    // 4 MB
    int* candCnt = (int*)(out0 + 5242880);                        // 128 KB
    unsigned short* whi = (unsigned short*)out1;                  // 512 KB
    // d_ws scratch:
    float* wsq = (float*)d_ws;                // 1024 f32

    k0w_pack<<<128, 256, 0, stream>>>(wemb, whi);
    k0z_pack<<<512, 256, 0, stream>>>(z, zhi);
    k1_wsq<<<4, 256, 0, stream>>>(wemb, wsq);
    k2s_screen<<<512, 256, 0, stream>>>(zhi, whi, wsq, candC, candCnt);
    k2r_rescore<<<512, 256, 0, stream>>>(z, wemb, wsq, candC, candCnt, oidx);
    k3_gather<<<Q_ELEMS / 4 / 256, 256, 0, stream>>>(z, wemb, oidx, out0, out1);
}

// Round 8
// 232.395 us; speedup vs baseline: 1.6852x; 1.6852x over previous
//
#include <hip/hip_runtime.h>
#include <cfloat>

// Geometry: z (32,256,32,32) f32, W (1024,256) f32.
// P = 32768 (p = n*1024+hw), K = 256, CODES = 1024.
// d_out = [quantized 8388608][straight_through 8388608][indices-as-float 32768]
// Strategy: bf16 MFMA screen (candidates within EPS of min) + exact fp32
// rescore (bitwise-identical chain). Rescore: 64 pos x 4 slots per block,
// z tile in LDS read lane-parallel via b128 (no broadcast-scalar LDS storms).

#define P_TOTAL   32768
#define N_CODES   1024
#define Q_ELEMS   8388608
#define EPS_SCREEN 1.0e-2f   // rigorous bf16-screen bound is ~2.4e-3; 4x margin
#define CAND_CAP  128

typedef __attribute__((ext_vector_type(8))) short bf16x8;
typedef __attribute__((ext_vector_type(4))) float f32x4;

#define GLOAD16(gsrc, ldst) \
  __builtin_amdgcn_global_load_lds((const __attribute__((address_space(1))) void*)(gsrc), \
                                   (__attribute__((address_space(3))) void*)(ldst), 16, 0, 0)

__device__ __forceinline__ unsigned short f2bf(float f) {   // RN-even f32->bf16
    unsigned u = __builtin_bit_cast(unsigned, f);
    u += 0x7FFF + ((u >> 16) & 1);
    return (unsigned short)(u >> 16);
}

__device__ __forceinline__ float sq_sep(float v) {
    float t = v * v;
    asm volatile("" : "+v"(t));
    return t;
}

// ---------------------------------------------------------------------------
// k0w: W[1024][256] f32 -> W_hi bf16; 16B granules XOR-swizzled in each 512B
// row: granule g of code c stored at slot g^(c&7).
// ---------------------------------------------------------------------------
__global__ void k0w_pack(const float* __restrict__ wemb, unsigned short* __restrict__ whi) {
    const int t = blockIdx.x * 256 + threadIdx.x;   // 32768 granules
    const int c = t >> 5, g = t & 31;
    const float4 v0 = *(const float4*)&wemb[(size_t)c * 256 + g * 8];
    const float4 v1 = *(const float4*)&wemb[(size_t)c * 256 + g * 8 + 4];
    bf16x8 hv;
    hv[0] = (short)f2bf(v0.x); hv[1] = (short)f2bf(v0.y);
    hv[2] = (short)f2bf(v0.z); hv[3] = (short)f2bf(v0.w);
    hv[4] = (short)f2bf(v1.x); hv[5] = (short)f2bf(v1.y);
    hv[6] = (short)f2bf(v1.z); hv[7] = (short)f2bf(v1.w);
    const int gs = g ^ (c & 7);
    *(bf16x8*)(whi + (size_t)c * 256 + gs * 8) = hv;
}

// ---------------------------------------------------------------------------
// k0z: z [n][k][hw] f32 -> z_hi [p][k] bf16 (transpose via LDS). grid 512.
// ---------------------------------------------------------------------------
#define T16S 280   // ushort stride: 560B rows (16B aligned)
__global__ void k0z_pack(const float* __restrict__ z, unsigned short* __restrict__ zhi) {
    __shared__ unsigned short t16[64 * T16S];   // 35,840 B
    const int tid = threadIdx.x;
    const int n = blockIdx.x >> 4, hc = blockIdx.x & 15;
    const int hw0 = hc * 64;
    const int w = tid >> 6, hl = tid & 63;
    #pragma unroll
    for (int i = 0; i < 64; ++i) {
        const int k = i * 4 + w;
        const float v = z[((size_t)(n * 256 + k) << 10) + hw0 + hl];
        t16[hl * T16S + k] = f2bf(v);
    }
    __syncthreads();
    const int row = tid >> 2, cp = tid & 3;
    const size_t p0 = (size_t)(n * 1024 + hw0);
    #pragma unroll
    for (int i = 0; i < 8; ++i) {
        const int chunk = i * 4 + cp;
        *(bf16x8*)(zhi + (p0 + row) * 256 + chunk * 8) =
            *(const bf16x8*)&t16[row * T16S + chunk * 8];
    }
}

// ---------------------------------------------------------------------------
// k1: wsq[c] only. numpy pairwise order (128+128, 8 accumulators).
// ---------------------------------------------------------------------------
__global__ void k1_wsq(const float* __restrict__ wemb, float* __restrict__ wsq) {
    const int c = blockIdx.x * 256 + threadIdx.x;
    const float* base = wemb + (size_t)c * 256;
    float half[2];
    #pragma unroll
    for (int h = 0; h < 2; ++h) {
        const float* x = base + h * 128;
        float r[8];
        #pragma unroll
        for (int j = 0; j < 8; ++j) r[j] = sq_sep(x[j]);
        for (int i = 8; i < 128; i += 8) {
            #pragma unroll
            for (int j = 0; j < 8; ++j) r[j] += sq_sep(x[i + j]);
        }
        half[h] = ((r[0] + r[1]) + (r[2] + r[3])) + ((r[4] + r[5]) + (r[6] + r[7]));
    }
    wsq[c] = half[0] + half[1];
}

// ---------------------------------------------------------------------------
// k2s: bf16 MFMA screen. Block = 64 pos (4 waves x 16), grid 512.
// Same as validated R5/R6/R7 except __launch_bounds__(256,4): 33KB LDS
// allows 4 blocks/CU — barrier drains overlap across blocks.
// ---------------------------------------------------------------------------
__launch_bounds__(256, 4)
__global__ void k2s_screen(const unsigned short* __restrict__ zhi,
                           const unsigned short* __restrict__ whi,
                           const float* __restrict__ wsq,
                           unsigned short* __restrict__ candC,
                           int* __restrict__ candCnt) {
    __shared__ unsigned short Bs[2][32 * 256];   // 16 KB x2
    __shared__ int cnt[64];
    const int tid = threadIdx.x, bid = blockIdx.x;
    const int w = tid >> 6, l = tid & 63;
    const int la = l & 15, kg = l >> 4;
    const int m0 = bid * 64 + w * 16;
    if (tid < 64) cnt[tid] = 0;

    bf16x8 af[8];
    #pragma unroll
    for (int ks = 0; ks < 8; ++ks)
        af[ks] = *(const bf16x8*)(zhi + (size_t)(m0 + la) * 256 + ks * 32 + kg * 8);

    float rg[4];
    #pragma unroll
    for (int r = 0; r < 4; ++r) rg[r] = FLT_MAX;

#define STAGEB(buf, cb_) do {                                                  \
    const unsigned short* src_ = whi + (size_t)(cb_) * 256;                    \
    _Pragma("unroll")                                                          \
    for (int i_ = 0; i_ < 4; ++i_)                                             \
        GLOAD16(src_ + i_ * 2048 + tid * 8, &Bs[buf][i_ * 2048 + tid * 8]);    \
} while (0)

    STAGEB(0, 0);
    __syncthreads();                      // cnt ready + Bs[0] landed

    for (int ch = 0; ch < 32; ++ch) {
        const int cur = ch & 1;
        const int cb = ch * 32;
        if (ch < 31) STAGEB(cur ^ 1, cb + 32);

        float wsqv[2];
        #pragma unroll
        for (int nf = 0; nf < 2; ++nf) wsqv[nf] = wsq[cb + nf * 16 + la];

        f32x4 acc[2];
        #pragma unroll
        for (int nf = 0; nf < 2; ++nf) acc[nf] = (f32x4){0.f, 0.f, 0.f, 0.f};

        #pragma unroll
        for (int ks = 0; ks < 8; ++ks) {
            bf16x8 bfv[2];
            #pragma unroll
            for (int nf = 0; nf < 2; ++nf) {
                const int cl = nf * 16 + la;
                const int slot = (ks * 4 + kg) ^ (cl & 7);   // un-swizzle
                bfv[nf] = *(const bf16x8*)&Bs[cur][cl * 256 + slot * 8];
            }
            #pragma unroll
            for (int nf = 0; nf < 2; ++nf)
                acc[nf] = __builtin_amdgcn_mfma_f32_16x16x32_bf16(
                    af[ks], bfv[nf], acc[nf], 0, 0, 0);
        }

        float da[2][4];
        #pragma unroll
        for (int nf = 0; nf < 2; ++nf)
            #pragma unroll
            for (int r = 0; r < 4; ++r)
                da[nf][r] = __builtin_fmaf(-2.f, acc[nf][r], wsqv[nf]);

        #pragma unroll
        for (int r = 0; r < 4; ++r) {
            float mv = fminf(da[0][r], da[1][r]);
            #pragma unroll
            for (int off = 1; off < 16; off <<= 1)
                mv = fminf(mv, __shfl_xor(mv, off));
            rg[r] = fminf(rg[r], mv);
        }

        #pragma unroll
        for (int nf = 0; nf < 2; ++nf)
            #pragma unroll
            for (int r = 0; r < 4; ++r)
                if (da[nf][r] <= rg[r] + EPS_SCREEN) {
                    const int plocal = w * 16 + kg * 4 + r;
                    const int slot = atomicAdd(&cnt[plocal], 1);
                    if (slot < CAND_CAP)
                        candC[(size_t)(bid * 64 + plocal) * CAND_CAP + slot] =
                            (unsigned short)(cb + nf * 16 + la);
                }

        __syncthreads();   // Bs[cur] reads done; Bs[cur^1] landed (vmcnt(0))
    }
#undef STAGEB

    if (tid < 64) candCnt[bid * 64 + tid] = cnt[tid];   // raw (overflow detectable)
}

// ---------------------------------------------------------------------------
// k2r v3: exact rescore, block = 64 positions x 4 candidate slots.
// z tile [64][256] fp32 staged coalesced into LDS with XOR-swizzle
// k^((row&7)*4) (multiple-of-4 XOR keeps b128 contiguity; reads <=2-way).
// Thread (pos,slot): zsq via exact numpy pairwise order; candidate dots via
// the exact sequential k-ascending fp32 fma chain (loads f32x4-grouped, fma
// order unchanged => bitwise-identical); d = fma(-2,dot,zsq)+wsq; lex-min
// (d,c) over slots (2x shfl_xor) == lowest-index tie-break.
// Overflow (count > CAP): full 1024-code scan, same chain, 4-way slot split.
// ---------------------------------------------------------------------------
__launch_bounds__(256, 2)
__global__ void k2r_rescore(const float* __restrict__ z, const float* __restrict__ wemb,
                            const float* __restrict__ wsq,
                            const unsigned short* __restrict__ candC,
                            const int* __restrict__ candCnt,
                            float* __restrict__ idx_out) {
    __shared__ float t32[64 * 256];   // 64 KB exactly
    const int tid = threadIdx.x;
    const int wv = tid >> 6, l = tid & 63;
    const int p0 = blockIdx.x * 64;
    const int n = p0 >> 10, hw0 = p0 & 1023;
    const int xml = (l & 7) * 4;

    // coalesced staging: wave wv covers k in {16i+wv*4 .. +4}; lanes span hw
    #pragma unroll
    for (int i = 0; i < 16; ++i) {
        const int k4 = i * 16 + wv * 4;
        const size_t zb = ((size_t)(n * 256 + k4) << 10) + hw0 + l;
        float4 v;
        v.x = z[zb];
        v.y = z[zb + 1024];
        v.z = z[zb + 2048];
        v.w = z[zb + 3072];
        *(float4*)&t32[l * 256 + (k4 ^ xml)] = v;
    }
    __syncthreads();

    const int pl = tid >> 2, slot = tid & 3;
    const int p = p0 + pl;
    const float* row = &t32[pl * 256];
    const int xm = (pl & 7) * 4;

    // zsq: numpy pairwise 128+128, 8 accumulators — exact k1 order/values
    float halfv[2];
    #pragma unroll
    for (int h = 0; h < 2; ++h) {
        float r[8];
        {
            const f32x4 a = *(const f32x4*)&row[(h * 128) ^ xm];
            const f32x4 b = *(const f32x4*)&row[(h * 128 + 4) ^ xm];
            #pragma unroll
            for (int j = 0; j < 4; ++j) { r[j] = sq_sep(a[j]); r[4 + j] = sq_sep(b[j]); }
        }
        for (int i = 8; i < 128; i += 8) {
            const f32x4 a = *(const f32x4*)&row[(h * 128 + i) ^ xm];
            const f32x4 b = *(const f32x4*)&row[(h * 128 + i + 4) ^ xm];
            #pragma unroll
            for (int j = 0; j < 4; ++j) { r[j] += sq_sep(a[j]); r[4 + j] += sq_sep(b[j]); }
        }
        halfv[h] = ((r[0] + r[1]) + (r[2] + r[3])) + ((r[4] + r[5]) + (r[6] + r[7]));
    }
    const float zsv = halfv[0] + halfv[1];

#define DOT_CHAIN(wb_, dot_) do {                                              \
    _Pragma("unroll")                                                          \
    for (int kb = 0; kb < 256; kb += 8) {                                      \
        const f32x4 za = *(const f32x4*)&row[kb ^ xm];                         \
        const f32x4 zb4 = *(const f32x4*)&row[(kb + 4) ^ xm];                  \
        const float4 wa = *(const float4*)&(wb_)[kb];                          \
        const float4 wc = *(const float4*)&(wb_)[kb + 4];                      \
        dot_ = __builtin_fmaf(za[0], wa.x, dot_);                              \
        dot_ = __builtin_fmaf(za[1], wa.y, dot_);                              \
        dot_ = __builtin_fmaf(za[2], wa.z, dot_);                              \
        dot_ = __builtin_fmaf(za[3], wa.w, dot_);                              \
        dot_ = __builtin_fmaf(zb4[0], wc.x, dot_);                             \
        dot_ = __builtin_fmaf(zb4[1], wc.y, dot_);                             \
        dot_ = __builtin_fmaf(zb4[2], wc.z, dot_);                             \
        dot_ = __builtin_fmaf(zb4[3], wc.w, dot_);                             \
    }                                                                          \
} while (0)

    const int count = candCnt[p];
    float bd = FLT_MAX;
    int bc = N_CODES;

    if (count <= CAND_CAP) {
        const int nr = (count + 3) >> 2;
        for (int rr = 0; rr < nr; ++rr) {
            const int s = rr * 4 + slot;
            if (s < count) {
                const int c = candC[(size_t)p * CAND_CAP + s];
                const float* wb = wemb + (size_t)c * 256;
                float dot = 0.f;
                DOT_CHAIN(wb, dot);
                const float d = __builtin_fmaf(-2.f, dot, zsv) + wsq[c];
                if (d < bd || (d == bd && c < bc)) { bd = d; bc = c; }
            }
        }
    } else {
        for (int rr = 0; rr < 256; ++rr) {
            const int c = rr * 4 + slot;
            const float* wb = wemb + (size_t)c * 256;
            float dot = 0.f;
            DOT_CHAIN(wb, dot);
            const float d = __builtin_fmaf(-2.f, dot, zsv) + wsq[c];
            if (d < bd || (d == bd && c < bc)) { bd = d; bc = c; }
        }
    }
#undef DOT_CHAIN

    // lex-min (d, c) across the 4 slots of this position
    #pragma unroll
    for (int off = 1; off < 4; off <<= 1) {
        const float od = __shfl_xor(bd, off);
        const int   oi = __shfl_xor(bc, off);
        if (od < bd || (od == bd && oi < bc)) { bd = od; bc = oi; }
    }
    if (slot == 0) idx_out[p] = (float)bc;
}

// ---------------------------------------------------------------------------
// k3: gather + straight-through, NCHW float4 writes
// ---------------------------------------------------------------------------
__global__ void k3_gather(const float* __restrict__ z, const float* __restrict__ wemb,
                          const float* __restrict__ idxf,
                          float* __restrict__ out0, float* __restrict__ out1) {
    const int t = blockIdx.x * 256 + threadIdx.x;
    const int hw4 = t & 255, c = (t >> 8) & 255, n = t >> 16;
    const size_t zo = (((size_t)(n * 256 + c)) << 10) + hw4 * 4;
    const float4 zv = *(const float4*)&z[zo];
    const float4 iv = *(const float4*)&idxf[n * 1024 + hw4 * 4];
    float4 qv, st;
    {
        const int i0 = (int)iv.x; qv.x = wemb[(size_t)i0 * 256 + c]; st.x = (qv.x - zv.x) + zv.x;
        const int i1 = (int)iv.y; qv.y = wemb[(size_t)i1 * 256 + c]; st.y = (qv.y - zv.y) + zv.y;
        const int i2 = (int)iv.z; qv.z = wemb[(size_t)i2 * 256 + c]; st.z = (qv.z - zv.z) + zv.z;
        const int i3 = (int)iv.w; qv.w = wemb[(size_t)i3 * 256 + c]; st.w = (qv.w - zv.w) + zv.w;
    }
    *(float4*)&out0[zo] = qv;
    *(float4*)&out1[zo] = st;
}

extern "C" void kernel_launch(void* const* d_in, const int* in_sizes, int n_in,
                              void* d_out, int out_size, void* d_ws, size_t ws_size,
                              hipStream_t stream) {
    const float* z = (const float*)d_in[0];
    const float* wemb = (const float*)d_in[1];
    float* out = (float*)d_out;
    float* out0 = out;                       // quantized (final)
    float* out1 = out + Q_ELEMS;             // straight_through (final)
    float* oidx = out + 2 * Q_ELEMS;         // indices-as-float (final)
    // big scratch inside d_out (all consumed before k3 overwrites):
    unsigned short* zhi = (unsigned short*)out0;                  // 16 MB  [0..4M floats)
    unsigned short* candC = (unsigned short*)(out0 + 4194304);    // 8 MB   [4M..6M floats)
    int* candCnt = (int*)(out0 + 6291456);                        // 128 KB [6M..6.03M)
    unsigned short* whi = (unsigned short*)out1;                  // 512 KB (out1 head)
    // d_ws scratch:
    float* wsq = (float*)d_ws;                // 1024 f32

    k0w_pack<<<128, 256, 0, stream>>>(wemb, whi);
    k0z_pack<<<512, 256, 0, stream>>>(z, zhi);
    k1_wsq<<<4, 256, 0, stream>>>(wemb, wsq);
    k2s_screen<<<512, 256, 0, stream>>>(zhi, whi, wsq, candC, candCnt);
    k2r_rescore<<<512, 256, 0, stream>>>(z, wemb, wsq, candC, candCnt, oidx);
    k3_gather<<<Q_ELEMS / 4 / 256, 256, 0, stream>>>(z, wemb, oidx, out0, out1);
}

// Round 9
// 228.135 us; speedup vs baseline: 1.7167x; 1.0187x over previous
//
#include <hip/hip_runtime.h>
#include <cfloat>

// Geometry: z (32,256,32,32) f32, W (1024,256) f32.
// P = 32768 (p = n*1024+hw), K = 256, CODES = 1024.
// d_out = [quantized 8388608][straight_through 8388608][indices-as-float 32768]
// Strategy: bf16 MFMA screen (candidates within EPS of min) + exact fp32
// rescore (bitwise-identical chain). Rescore: 32 pos x 8 slots per block,
// 32KB LDS -> 4 blocks/CU; candidate metadata prefetched over staging.

#define P_TOTAL   32768
#define N_CODES   1024
#define Q_ELEMS   8388608
#define EPS_SCREEN 1.0e-2f   // rigorous bf16-screen bound is ~2.4e-3; 4x margin
#define CAND_CAP  128

typedef __attribute__((ext_vector_type(8))) short bf16x8;
typedef __attribute__((ext_vector_type(4))) float f32x4;

#define GLOAD16(gsrc, ldst) \
  __builtin_amdgcn_global_load_lds((const __attribute__((address_space(1))) void*)(gsrc), \
                                   (__attribute__((address_space(3))) void*)(ldst), 16, 0, 0)

__device__ __forceinline__ unsigned short f2bf(float f) {   // RN-even f32->bf16
    unsigned u = __builtin_bit_cast(unsigned, f);
    u += 0x7FFF + ((u >> 16) & 1);
    return (unsigned short)(u >> 16);
}

__device__ __forceinline__ float sq_sep(float v) {
    float t = v * v;
    asm volatile("" : "+v"(t));
    return t;
}

// ---------------------------------------------------------------------------
// k0w: W[1024][256] f32 -> W_hi bf16; 16B granules XOR-swizzled in each 512B
// row: granule g of code c stored at slot g^(c&7).
// ---------------------------------------------------------------------------
__global__ void k0w_pack(const float* __restrict__ wemb, unsigned short* __restrict__ whi) {
    const int t = blockIdx.x * 256 + threadIdx.x;   // 32768 granules
    const int c = t >> 5, g = t & 31;
    const float4 v0 = *(const float4*)&wemb[(size_t)c * 256 + g * 8];
    const float4 v1 = *(const float4*)&wemb[(size_t)c * 256 + g * 8 + 4];
    bf16x8 hv;
    hv[0] = (short)f2bf(v0.x); hv[1] = (short)f2bf(v0.y);
    hv[2] = (short)f2bf(v0.z); hv[3] = (short)f2bf(v0.w);
    hv[4] = (short)f2bf(v1.x); hv[5] = (short)f2bf(v1.y);
    hv[6] = (short)f2bf(v1.z); hv[7] = (short)f2bf(v1.w);
    const int gs = g ^ (c & 7);
    *(bf16x8*)(whi + (size_t)c * 256 + gs * 8) = hv;
}

// ---------------------------------------------------------------------------
// k0z: z [n][k][hw] f32 -> z_hi [p][k] bf16 (transpose via LDS). grid 512.
// ---------------------------------------------------------------------------
#define T16S 280   // ushort stride: 560B rows (16B aligned)
__global__ void k0z_pack(const float* __restrict__ z, unsigned short* __restrict__ zhi) {
    __shared__ unsigned short t16[64 * T16S];   // 35,840 B
    const int tid = threadIdx.x;
    const int n = blockIdx.x >> 4, hc = blockIdx.x & 15;
    const int hw0 = hc * 64;
    const int w = tid >> 6, hl = tid & 63;
    #pragma unroll
    for (int i = 0; i < 64; ++i) {
        const int k = i * 4 + w;
        const float v = z[((size_t)(n * 256 + k) << 10) + hw0 + hl];
        t16[hl * T16S + k] = f2bf(v);
    }
    __syncthreads();
    const int row = tid >> 2, cp = tid & 3;
    const size_t p0 = (size_t)(n * 1024 + hw0);
    #pragma unroll
    for (int i = 0; i < 8; ++i) {
        const int chunk = i * 4 + cp;
        *(bf16x8*)(zhi + (p0 + row) * 256 + chunk * 8) =
            *(const bf16x8*)&t16[row * T16S + chunk * 8];
    }
}

// ---------------------------------------------------------------------------
// k1: wsq[c] only. numpy pairwise order (128+128, 8 accumulators).
// ---------------------------------------------------------------------------
__global__ void k1_wsq(const float* __restrict__ wemb, float* __restrict__ wsq) {
    const int c = blockIdx.x * 256 + threadIdx.x;
    const float* base = wemb + (size_t)c * 256;
    float half[2];
    #pragma unroll
    for (int h = 0; h < 2; ++h) {
        const float* x = base + h * 128;
        float r[8];
        #pragma unroll
        for (int j = 0; j < 8; ++j) r[j] = sq_sep(x[j]);
        for (int i = 8; i < 128; i += 8) {
            #pragma unroll
            for (int j = 0; j < 8; ++j) r[j] += sq_sep(x[i + j]);
        }
        half[h] = ((r[0] + r[1]) + (r[2] + r[3])) + ((r[4] + r[5]) + (r[6] + r[7]));
    }
    wsq[c] = half[0] + half[1];
}

// ---------------------------------------------------------------------------
// k2s: bf16 MFMA screen. Block = 64 pos (4 waves x 16), grid 512.
// UNCHANGED from validated R8 (incl. __launch_bounds__(256,4)).
// ---------------------------------------------------------------------------
__launch_bounds__(256, 4)
__global__ void k2s_screen(const unsigned short* __restrict__ zhi,
                           const unsigned short* __restrict__ whi,
                           const float* __restrict__ wsq,
                           unsigned short* __restrict__ candC,
                           int* __restrict__ candCnt) {
    __shared__ unsigned short Bs[2][32 * 256];   // 16 KB x2
    __shared__ int cnt[64];
    const int tid = threadIdx.x, bid = blockIdx.x;
    const int w = tid >> 6, l = tid & 63;
    const int la = l & 15, kg = l >> 4;
    const int m0 = bid * 64 + w * 16;
    if (tid < 64) cnt[tid] = 0;

    bf16x8 af[8];
    #pragma unroll
    for (int ks = 0; ks < 8; ++ks)
        af[ks] = *(const bf16x8*)(zhi + (size_t)(m0 + la) * 256 + ks * 32 + kg * 8);

    float rg[4];
    #pragma unroll
    for (int r = 0; r < 4; ++r) rg[r] = FLT_MAX;

#define STAGEB(buf, cb_) do {                                                  \
    const unsigned short* src_ = whi + (size_t)(cb_) * 256;                    \
    _Pragma("unroll")                                                          \
    for (int i_ = 0; i_ < 4; ++i_)                                             \
        GLOAD16(src_ + i_ * 2048 + tid * 8, &Bs[buf][i_ * 2048 + tid * 8]);    \
} while (0)

    STAGEB(0, 0);
    __syncthreads();                      // cnt ready + Bs[0] landed

    for (int ch = 0; ch < 32; ++ch) {
        const int cur = ch & 1;
        const int cb = ch * 32;
        if (ch < 31) STAGEB(cur ^ 1, cb + 32);

        float wsqv[2];
        #pragma unroll
        for (int nf = 0; nf < 2; ++nf) wsqv[nf] = wsq[cb + nf * 16 + la];

        f32x4 acc[2];
        #pragma unroll
        for (int nf = 0; nf < 2; ++nf) acc[nf] = (f32x4){0.f, 0.f, 0.f, 0.f};

        #pragma unroll
        for (int ks = 0; ks < 8; ++ks) {
            bf16x8 bfv[2];
            #pragma unroll
            for (int nf = 0; nf < 2; ++nf) {
                const int cl = nf * 16 + la;
                const int slot = (ks * 4 + kg) ^ (cl & 7);   // un-swizzle
                bfv[nf] = *(const bf16x8*)&Bs[cur][cl * 256 + slot * 8];
            }
            #pragma unroll
            for (int nf = 0; nf < 2; ++nf)
                acc[nf] = __builtin_amdgcn_mfma_f32_16x16x32_bf16(
                    af[ks], bfv[nf], acc[nf], 0, 0, 0);
        }

        float da[2][4];
        #pragma unroll
        for (int nf = 0; nf < 2; ++nf)
            #pragma unroll
            for (int r = 0; r < 4; ++r)
                da[nf][r] = __builtin_fmaf(-2.f, acc[nf][r], wsqv[nf]);

        #pragma unroll
        for (int r = 0; r < 4; ++r) {
            float mv = fminf(da[0][r], da[1][r]);
            #pragma unroll
            for (int off = 1; off < 16; off <<= 1)
                mv = fminf(mv, __shfl_xor(mv, off));
            rg[r] = fminf(rg[r], mv);
        }

        #pragma unroll
        for (int nf = 0; nf < 2; ++nf)
            #pragma unroll
            for (int r = 0; r < 4; ++r)
                if (da[nf][r] <= rg[r] + EPS_SCREEN) {
                    const int plocal = w * 16 + kg * 4 + r;
                    const int slot = atomicAdd(&cnt[plocal], 1);
                    if (slot < CAND_CAP)
                        candC[(size_t)(bid * 64 + plocal) * CAND_CAP + slot] =
                            (unsigned short)(cb + nf * 16 + la);
                }

        __syncthreads();   // Bs[cur] reads done; Bs[cur^1] landed (vmcnt(0))
    }
#undef STAGEB

    if (tid < 64) candCnt[bid * 64 + tid] = cnt[tid];   // raw (overflow detectable)
}

// ---------------------------------------------------------------------------
// k2r v4: exact rescore, block = 32 positions x 8 candidate slots.
// 32KB LDS -> 4 blocks/CU (launch_bounds(256,4)); grid 1024.
// Candidate metadata (count + round-0 index) prefetched BEFORE staging so the
// dependent gather chain overlaps the z-tile loads.
// All fp32 arithmetic (zsq numpy-pairwise; k-ascending fma DOT_CHAIN;
// d = fma(-2,dot,zsq)+wsq; lex-min (d,c)) is instruction-identical to the
// validated R8 kernel. XOR swizzle k^((row&7)*4) measured conflict-free (R8).
// ---------------------------------------------------------------------------
__launch_bounds__(256, 4)
__global__ void k2r_rescore(const float* __restrict__ z, const float* __restrict__ wemb,
                            const float* __restrict__ wsq,
                            const unsigned short* __restrict__ candC,
                            const int* __restrict__ candCnt,
                            float* __restrict__ idx_out) {
    __shared__ float t32[32 * 256];   // 32 KB
    const int tid = threadIdx.x;
    const int wv = tid >> 6, l = tid & 63;
    const int p0 = blockIdx.x * 32;
    const int n = p0 >> 10, hw0 = p0 & 1023;

    // ---- prefetch rescore metadata (overlaps staging) ----
    const int pl = tid >> 3, slot = tid & 7;
    const int p = p0 + pl;
    const int count = candCnt[p];
    const int c0 = candC[(size_t)p * CAND_CAP + slot];   // valid mem; used iff slot<count

    // ---- stage z tile [32 hw][256 k] fp32, coalesced, b128 LDS writes ----
    const int row = l & 31;
    const int xmr = (row & 7) * 4;
    #pragma unroll
    for (int i = 0; i < 8; ++i) {
        const int k4 = i * 32 + wv * 8 + (l >> 5) * 4;
        const size_t zb = ((size_t)(n * 256 + k4) << 10) + hw0 + row;
        float4 v;
        v.x = z[zb];
        v.y = z[zb + 1024];
        v.z = z[zb + 2048];
        v.w = z[zb + 3072];
        *(float4*)&t32[row * 256 + (k4 ^ xmr)] = v;
    }
    __syncthreads();

    const float* zrow = &t32[pl * 256];
    const int xm = (pl & 7) * 4;

    // ---- zsq: numpy pairwise 128+128, 8 accumulators (exact k1 order) ----
    float halfv[2];
    #pragma unroll
    for (int h = 0; h < 2; ++h) {
        float r[8];
        {
            const f32x4 a = *(const f32x4*)&zrow[(h * 128) ^ xm];
            const f32x4 b = *(const f32x4*)&zrow[(h * 128 + 4) ^ xm];
            #pragma unroll
            for (int j = 0; j < 4; ++j) { r[j] = sq_sep(a[j]); r[4 + j] = sq_sep(b[j]); }
        }
        for (int i = 8; i < 128; i += 8) {
            const f32x4 a = *(const f32x4*)&zrow[(h * 128 + i) ^ xm];
            const f32x4 b = *(const f32x4*)&zrow[(h * 128 + i + 4) ^ xm];
            #pragma unroll
            for (int j = 0; j < 4; ++j) { r[j] += sq_sep(a[j]); r[4 + j] += sq_sep(b[j]); }
        }
        halfv[h] = ((r[0] + r[1]) + (r[2] + r[3])) + ((r[4] + r[5]) + (r[6] + r[7]));
    }
    const float zsv = halfv[0] + halfv[1];

#define DOT_CHAIN(wb_, dot_) do {                                              \
    _Pragma("unroll")                                                          \
    for (int kb = 0; kb < 256; kb += 8) {                                      \
        const f32x4 za = *(const f32x4*)&zrow[kb ^ xm];                        \
        const f32x4 zb4 = *(const f32x4*)&zrow[(kb + 4) ^ xm];                 \
        const float4 wa = *(const float4*)&(wb_)[kb];                          \
        const float4 wc = *(const float4*)&(wb_)[kb + 4];                      \
        dot_ = __builtin_fmaf(za[0], wa.x, dot_);                              \
        dot_ = __builtin_fmaf(za[1], wa.y, dot_);                              \
        dot_ = __builtin_fmaf(za[2], wa.z, dot_);                              \
        dot_ = __builtin_fmaf(za[3], wa.w, dot_);                              \
        dot_ = __builtin_fmaf(zb4[0], wc.x, dot_);                             \
        dot_ = __builtin_fmaf(zb4[1], wc.y, dot_);                             \
        dot_ = __builtin_fmaf(zb4[2], wc.z, dot_);                             \
        dot_ = __builtin_fmaf(zb4[3], wc.w, dot_);                             \
    }                                                                          \
} while (0)

    float bd = FLT_MAX;
    int bc = N_CODES;

    if (count <= CAND_CAP) {
        const int nr = (count + 7) >> 3;
        for (int rr = 0; rr < nr; ++rr) {
            const int s = rr * 8 + slot;
            if (s < count) {
                const int c = (rr == 0) ? c0 : candC[(size_t)p * CAND_CAP + s];
                const float* wb = wemb + (size_t)c * 256;
                float dot = 0.f;
                DOT_CHAIN(wb, dot);
                const float d = __builtin_fmaf(-2.f, dot, zsv) + wsq[c];
                if (d < bd || (d == bd && c < bc)) { bd = d; bc = c; }
            }
        }
    } else {
        for (int rr = 0; rr < 128; ++rr) {
            const int c = rr * 8 + slot;
            const float* wb = wemb + (size_t)c * 256;
            float dot = 0.f;
            DOT_CHAIN(wb, dot);
            const float d = __builtin_fmaf(-2.f, dot, zsv) + wsq[c];
            if (d < bd || (d == bd && c < bc)) { bd = d; bc = c; }
        }
    }
#undef DOT_CHAIN

    // lex-min (d, c) across the 8 slots of this position
    #pragma unroll
    for (int off = 1; off < 8; off <<= 1) {
        const float od = __shfl_xor(bd, off);
        const int   oi = __shfl_xor(bc, off);
        if (od < bd || (od == bd && oi < bc)) { bd = od; bc = oi; }
    }
    if (slot == 0) idx_out[p] = (float)bc;
}

// ---------------------------------------------------------------------------
// k3: gather + straight-through, NCHW float4 writes
// ---------------------------------------------------------------------------
__global__ void k3_gather(const float* __restrict__ z, const float* __restrict__ wemb,
                          const float* __restrict__ idxf,
                          float* __restrict__ out0, float* __restrict__ out1) {
    const int t = blockIdx.x * 256 + threadIdx.x;
    const int hw4 = t & 255, c = (t >> 8) & 255, n = t >> 16;
    const size_t zo = (((size_t)(n * 256 + c)) << 10) + hw4 * 4;
    const float4 zv = *(const float4*)&z[zo];
    const float4 iv = *(const float4*)&idxf[n * 1024 + hw4 * 4];
    float4 qv, st;
    {
        const int i0 = (int)iv.x; qv.x = wemb[(size_t)i0 * 256 + c]; st.x = (qv.x - zv.x) + zv.x;
        const int i1 = (int)iv.y; qv.y = wemb[(size_t)i1 * 256 + c]; st.y = (qv.y - zv.y) + zv.y;
        const int i2 = (int)iv.z; qv.z = wemb[(size_t)i2 * 256 + c]; st.z = (qv.z - zv.z) + zv.z;
        const int i3 = (int)iv.w; qv.w = wemb[(size_t)i3 * 256 + c]; st.w = (qv.w - zv.w) + zv.w;
    }
    *(float4*)&out0[zo] = qv;
    *(float4*)&out1[zo] = st;
}

extern "C" void kernel_launch(void* const* d_in, const int* in_sizes, int n_in,
                              void* d_out, int out_size, void* d_ws, size_t ws_size,
                              hipStream_t stream) {
    const float* z = (const float*)d_in[0];
    const float* wemb = (const float*)d_in[1];
    float* out = (float*)d_out;
    float* out0 = out;                       // quantized (final)
    float* out1 = out + Q_ELEMS;             // straight_through (final)
    float* oidx = out + 2 * Q_ELEMS;         // indices-as-float (final)
    // big scratch inside d_out (all consumed before k3 overwrites):
    unsigned short* zhi = (unsigned short*)out0;                  // 16 MB  [0..4M floats)
    unsigned short* candC = (unsigned short*)(out0 + 4194304);    // 8 MB   [4M..6M floats)
    int* candCnt = (int*)(out0 + 6291456);                        // 128 KB [6M..6.03M)
    unsigned short* whi = (unsigned short*)out1;                  // 512 KB (out1 head)
    // d_ws scratch:
    float* wsq = (float*)d_ws;                // 1024 f32

    k0w_pack<<<128, 256, 0, stream>>>(wemb, whi);
    k0z_pack<<<512, 256, 0, stream>>>(z, zhi);
    k1_wsq<<<4, 256, 0, stream>>>(wemb, wsq);
    k2s_screen<<<512, 256, 0, stream>>>(zhi, whi, wsq, candC, candCnt);
    k2r_rescore<<<P_TOTAL / 32, 256, 0, stream>>>(z, wemb, wsq, candC, candCnt, oidx);
    k3_gather<<<Q_ELEMS / 4 / 256, 256, 0, stream>>>(z, wemb, oidx, out0, out1);
}

// Round 10
// 192.815 us; speedup vs baseline: 2.0312x; 1.1832x over previous
//
#include <hip/hip_runtime.h>
#include <cfloat>

// Geometry: z (32,256,32,32) f32, W (1024,256) f32.
// P = 32768 (p = n*1024+hw), K = 256, CODES = 1024.
// d_out = [quantized 8388608][straight_through 8388608][indices-as-float 32768]
// Strategy: bf16 MFMA screen (candidates within EPS of min, halves in
// parallel, global atomic slots) + exact fp32 rescore (bitwise-identical
// chain). k3 gathers via f32 W-transpose staged in LDS (all coalesced).

#define P_TOTAL   32768
#define N_CODES   1024
#define Q_ELEMS   8388608
#define EPS_SCREEN 4.0e-3f   // rigorous bf16-screen bound ~1.3e-3; 3x margin
#define CAND_CAP  128

typedef __attribute__((ext_vector_type(8))) short bf16x8;
typedef __attribute__((ext_vector_type(4))) float f32x4;

#define GLOAD16(gsrc, ldst) \
  __builtin_amdgcn_global_load_lds((const __attribute__((address_space(1))) void*)(gsrc), \
                                   (__attribute__((address_space(3))) void*)(ldst), 16, 0, 0)

__device__ __forceinline__ unsigned short f2bf(float f) {   // RN-even f32->bf16
    unsigned u = __builtin_bit_cast(unsigned, f);
    u += 0x7FFF + ((u >> 16) & 1);
    return (unsigned short)(u >> 16);
}

__device__ __forceinline__ float sq_sep(float v) {
    float t = v * v;
    asm volatile("" : "+v"(t));
    return t;
}

// ---------------------------------------------------------------------------
// k0t: W[1024][256] -> Wtf[256][1024] f32 (exact copy; validated in R2/R3).
// ---------------------------------------------------------------------------
__global__ void k0t_transpose(const float* __restrict__ wemb, float* __restrict__ wt) {
    __shared__ float tile[64 * 65];
    const int tid = threadIdx.x;
    const int ct = blockIdx.x >> 2, kt = blockIdx.x & 3;
    const int c0 = ct * 64, k0 = kt * 64;
    const int rr = tid >> 4, cg = tid & 15;
    #pragma unroll
    for (int i = 0; i < 4; ++i) {
        const int row = i * 16 + rr;
        const float4 v = *(const float4*)&wemb[(size_t)(c0 + row) * 256 + k0 + cg * 4];
        tile[row * 65 + cg * 4 + 0] = v.x;
        tile[row * 65 + cg * 4 + 1] = v.y;
        tile[row * 65 + cg * 4 + 2] = v.z;
        tile[row * 65 + cg * 4 + 3] = v.w;
    }
    __syncthreads();
    #pragma unroll
    for (int i = 0; i < 4; ++i) {
        const int krow = i * 16 + rr;
        float4 v;
        v.x = tile[(cg * 4 + 0) * 65 + krow];
        v.y = tile[(cg * 4 + 1) * 65 + krow];
        v.z = tile[(cg * 4 + 2) * 65 + krow];
        v.w = tile[(cg * 4 + 3) * 65 + krow];
        *(float4*)&wt[(size_t)(k0 + krow) * 1024 + c0 + cg * 4] = v;
    }
}

// ---------------------------------------------------------------------------
// k0w: W -> W_hi bf16; 16B granules XOR-swizzled (slot g^(c&7) per 512B row).
// ---------------------------------------------------------------------------
__global__ void k0w_pack(const float* __restrict__ wemb, unsigned short* __restrict__ whi) {
    const int t = blockIdx.x * 256 + threadIdx.x;   // 32768 granules
    const int c = t >> 5, g = t & 31;
    const float4 v0 = *(const float4*)&wemb[(size_t)c * 256 + g * 8];
    const float4 v1 = *(const float4*)&wemb[(size_t)c * 256 + g * 8 + 4];
    bf16x8 hv;
    hv[0] = (short)f2bf(v0.x); hv[1] = (short)f2bf(v0.y);
    hv[2] = (short)f2bf(v0.z); hv[3] = (short)f2bf(v0.w);
    hv[4] = (short)f2bf(v1.x); hv[5] = (short)f2bf(v1.y);
    hv[6] = (short)f2bf(v1.z); hv[7] = (short)f2bf(v1.w);
    const int gs = g ^ (c & 7);
    *(bf16x8*)(whi + (size_t)c * 256 + gs * 8) = hv;
}

// ---------------------------------------------------------------------------
// k0z: z [n][k][hw] f32 -> z_hi [p][k] bf16 (transpose via LDS). grid 512.
// ---------------------------------------------------------------------------
#define T16S 280   // ushort stride: 560B rows (16B aligned)
__global__ void k0z_pack(const float* __restrict__ z, unsigned short* __restrict__ zhi) {
    __shared__ unsigned short t16[64 * T16S];   // 35,840 B
    const int tid = threadIdx.x;
    const int n = blockIdx.x >> 4, hc = blockIdx.x & 15;
    const int hw0 = hc * 64;
    const int w = tid >> 6, hl = tid & 63;
    #pragma unroll
    for (int i = 0; i < 64; ++i) {
        const int k = i * 4 + w;
        const float v = z[((size_t)(n * 256 + k) << 10) + hw0 + hl];
        t16[hl * T16S + k] = f2bf(v);
    }
    __syncthreads();
    const int row = tid >> 2, cp = tid & 3;
    const size_t p0 = (size_t)(n * 1024 + hw0);
    #pragma unroll
    for (int i = 0; i < 8; ++i) {
        const int chunk = i * 4 + cp;
        *(bf16x8*)(zhi + (p0 + row) * 256 + chunk * 8) =
            *(const bf16x8*)&t16[row * T16S + chunk * 8];
    }
}

// ---------------------------------------------------------------------------
// k1: blocks 0-3: wsq[c] (numpy pairwise order). blocks 4-131: zero candCnt.
// ---------------------------------------------------------------------------
__global__ void k1_wsq(const float* __restrict__ wemb, float* __restrict__ wsq,
                       int* __restrict__ candCnt) {
    const int b = blockIdx.x, tid = threadIdx.x;
    if (b >= 4) { candCnt[(b - 4) * 256 + tid] = 0; return; }
    const int c = b * 256 + tid;
    const float* base = wemb + (size_t)c * 256;
    float half[2];
    #pragma unroll
    for (int h = 0; h < 2; ++h) {
        const float* x = base + h * 128;
        float r[8];
        #pragma unroll
        for (int j = 0; j < 8; ++j) r[j] = sq_sep(x[j]);
        for (int i = 8; i < 128; i += 8) {
            #pragma unroll
            for (int j = 0; j < 8; ++j) r[j] += sq_sep(x[i + j]);
        }
        half[h] = ((r[0] + r[1]) + (r[2] + r[3])) + ((r[4] + r[5]) + (r[6] + r[7]));
    }
    wsq[c] = half[0] + half[1];
}

// ---------------------------------------------------------------------------
// k2s: bf16 MFMA screen. Block = 64 pos x 512 codes (one half); grid 1024
// (pgrp = bid>>1, half = bid&1) -> 4 blocks/CU. Slots via GLOBAL atomicAdd
// (order-independent downstream). Per-half running-min threshold is a
// superset of the global-min threshold -> exact argmin + ties always kept.
// MFMA/fragment/swizzle structure unchanged from validated R5-R9.
// ---------------------------------------------------------------------------
__launch_bounds__(256, 4)
__global__ void k2s_screen(const unsigned short* __restrict__ zhi,
                           const unsigned short* __restrict__ whi,
                           const float* __restrict__ wsq,
                           unsigned short* __restrict__ candC,
                           int* __restrict__ candCnt) {
    __shared__ unsigned short Bs[2][32 * 256];   // 16 KB x2
    const int tid = threadIdx.x, bid = blockIdx.x;
    const int pgrp = bid >> 1, half = bid & 1;
    const int w = tid >> 6, l = tid & 63;
    const int la = l & 15, kg = l >> 4;
    const int m0 = pgrp * 64 + w * 16;
    const int cb0 = half * 512;

    bf16x8 af[8];
    #pragma unroll
    for (int ks = 0; ks < 8; ++ks)
        af[ks] = *(const bf16x8*)(zhi + (size_t)(m0 + la) * 256 + ks * 32 + kg * 8);

    float rg[4];
    #pragma unroll
    for (int r = 0; r < 4; ++r) rg[r] = FLT_MAX;

#define STAGEB(buf, cb_) do {                                                  \
    const unsigned short* src_ = whi + (size_t)(cb_) * 256;                    \
    _Pragma("unroll")                                                          \
    for (int i_ = 0; i_ < 4; ++i_)                                             \
        GLOAD16(src_ + i_ * 2048 + tid * 8, &Bs[buf][i_ * 2048 + tid * 8]);    \
} while (0)

    STAGEB(0, cb0);
    __syncthreads();                      // Bs[0] landed

    for (int ch = 0; ch < 16; ++ch) {
        const int cur = ch & 1;
        const int cb = cb0 + ch * 32;
        if (ch < 15) STAGEB(cur ^ 1, cb + 32);

        float wsqv[2];
        #pragma unroll
        for (int nf = 0; nf < 2; ++nf) wsqv[nf] = wsq[cb + nf * 16 + la];

        f32x4 acc[2];
        #pragma unroll
        for (int nf = 0; nf < 2; ++nf) acc[nf] = (f32x4){0.f, 0.f, 0.f, 0.f};

        #pragma unroll
        for (int ks = 0; ks < 8; ++ks) {
            bf16x8 bfv[2];
            #pragma unroll
            for (int nf = 0; nf < 2; ++nf) {
                const int cl = nf * 16 + la;
                const int slot = (ks * 4 + kg) ^ (cl & 7);   // un-swizzle
                bfv[nf] = *(const bf16x8*)&Bs[cur][cl * 256 + slot * 8];
            }
            #pragma unroll
            for (int nf = 0; nf < 2; ++nf)
                acc[nf] = __builtin_amdgcn_mfma_f32_16x16x32_bf16(
                    af[ks], bfv[nf], acc[nf], 0, 0, 0);
        }

        float da[2][4];
        #pragma unroll
        for (int nf = 0; nf < 2; ++nf)
            #pragma unroll
            for (int r = 0; r < 4; ++r)
                da[nf][r] = __builtin_fmaf(-2.f, acc[nf][r], wsqv[nf]);

        #pragma unroll
        for (int r = 0; r < 4; ++r) {
            float mv = fminf(da[0][r], da[1][r]);
            #pragma unroll
            for (int off = 1; off < 16; off <<= 1)
                mv = fminf(mv, __shfl_xor(mv, off));
            rg[r] = fminf(rg[r], mv);
        }

        #pragma unroll
        for (int nf = 0; nf < 2; ++nf)
            #pragma unroll
            for (int r = 0; r < 4; ++r)
                if (da[nf][r] <= rg[r] + EPS_SCREEN) {
                    const int p = pgrp * 64 + w * 16 + kg * 4 + r;
                    const int slot = atomicAdd(&candCnt[p], 1);
                    if (slot < CAND_CAP)
                        candC[(size_t)p * CAND_CAP + slot] =
                            (unsigned short)(cb + nf * 16 + la);
                }

        __syncthreads();   // Bs[cur] reads done; Bs[cur^1] landed (vmcnt(0))
    }
#undef STAGEB
}

// ---------------------------------------------------------------------------
// k2r: exact rescore, block = 32 positions x 8 candidate slots (UNCHANGED
// from validated R9 — bitwise-identical fp32 chains; lex-min is slot-order-
// independent so k2s's atomic slot ordering cannot affect the result).
// ---------------------------------------------------------------------------
__launch_bounds__(256, 4)
__global__ void k2r_rescore(const float* __restrict__ z, const float* __restrict__ wemb,
                            const float* __restrict__ wsq,
                            const unsigned short* __restrict__ candC,
                            const int* __restrict__ candCnt,
                            float* __restrict__ idx_out) {
    __shared__ float t32[32 * 256];   // 32 KB
    const int tid = threadIdx.x;
    const int wv = tid >> 6, l = tid & 63;
    const int p0 = blockIdx.x * 32;
    const int n = p0 >> 10, hw0 = p0 & 1023;

    // ---- prefetch rescore metadata (overlaps staging) ----
    const int pl = tid >> 3, slot = tid & 7;
    const int p = p0 + pl;
    const int count = candCnt[p];
    const int c0 = candC[(size_t)p * CAND_CAP + slot];   // used iff slot<count

    // ---- stage z tile [32 hw][256 k] fp32, coalesced, b128 LDS writes ----
    const int row = l & 31;
    const int xmr = (row & 7) * 4;
    #pragma unroll
    for (int i = 0; i < 8; ++i) {
        const int k4 = i * 32 + wv * 8 + (l >> 5) * 4;
        const size_t zb = ((size_t)(n * 256 + k4) << 10) + hw0 + row;
        float4 v;
        v.x = z[zb];
        v.y = z[zb + 1024];
        v.z = z[zb + 2048];
        v.w = z[zb + 3072];
        *(float4*)&t32[row * 256 + (k4 ^ xmr)] = v;
    }
    __syncthreads();

    const float* zrow = &t32[pl * 256];
    const int xm = (pl & 7) * 4;

    // ---- zsq: numpy pairwise 128+128, 8 accumulators (exact k1 order) ----
    float halfv[2];
    #pragma unroll
    for (int h = 0; h < 2; ++h) {
        float r[8];
        {
            const f32x4 a = *(const f32x4*)&zrow[(h * 128) ^ xm];
            const f32x4 b = *(const f32x4*)&zrow[(h * 128 + 4) ^ xm];
            #pragma unroll
            for (int j = 0; j < 4; ++j) { r[j] = sq_sep(a[j]); r[4 + j] = sq_sep(b[j]); }
        }
        for (int i = 8; i < 128; i += 8) {
            const f32x4 a = *(const f32x4*)&zrow[(h * 128 + i) ^ xm];
            const f32x4 b = *(const f32x4*)&zrow[(h * 128 + i + 4) ^ xm];
            #pragma unroll
            for (int j = 0; j < 4; ++j) { r[j] += sq_sep(a[j]); r[4 + j] += sq_sep(b[j]); }
        }
        halfv[h] = ((r[0] + r[1]) + (r[2] + r[3])) + ((r[4] + r[5]) + (r[6] + r[7]));
    }
    const float zsv = halfv[0] + halfv[1];

#define DOT_CHAIN(wb_, dot_) do {                                              \
    _Pragma("unroll")                                                          \
    for (int kb = 0; kb < 256; kb += 8) {                                      \
        const f32x4 za = *(const f32x4*)&zrow[kb ^ xm];                        \
        const f32x4 zb4 = *(const f32x4*)&zrow[(kb + 4) ^ xm];                 \
        const float4 wa = *(const float4*)&(wb_)[kb];                          \
        const float4 wc = *(const float4*)&(wb_)[kb + 4];                      \
        dot_ = __builtin_fmaf(za[0], wa.x, dot_);                              \
        dot_ = __builtin_fmaf(za[1], wa.y, dot_);                              \
        dot_ = __builtin_fmaf(za[2], wa.z, dot_);                              \
        dot_ = __builtin_fmaf(za[3], wa.w, dot_);                              \
        dot_ = __builtin_fmaf(zb4[0], wc.x, dot_);                             \
        dot_ = __builtin_fmaf(zb4[1], wc.y, dot_);                             \
        dot_ = __builtin_fmaf(zb4[2], wc.z, dot_);                             \
        dot_ = __builtin_fmaf(zb4[3], wc.w, dot_);                             \
    }                                                                          \
} while (0)

    float bd = FLT_MAX;
    int bc = N_CODES;

    if (count <= CAND_CAP) {
        const int nr = (count + 7) >> 3;
        for (int rr = 0; rr < nr; ++rr) {
            const int s = rr * 8 + slot;
            if (s < count) {
                const int c = (rr == 0) ? c0 : candC[(size_t)p * CAND_CAP + s];
                const float* wb = wemb + (size_t)c * 256;
                float dot = 0.f;
                DOT_CHAIN(wb, dot);
                const float d = __builtin_fmaf(-2.f, dot, zsv) + wsq[c];
                if (d < bd || (d == bd && c < bc)) { bd = d; bc = c; }
            }
        }
    } else {
        for (int rr = 0; rr < 128; ++rr) {
            const int c = rr * 8 + slot;
            const float* wb = wemb + (size_t)c * 256;
            float dot = 0.f;
            DOT_CHAIN(wb, dot);
            const float d = __builtin_fmaf(-2.f, dot, zsv) + wsq[c];
            if (d < bd || (d == bd && c < bc)) { bd = d; bc = c; }
        }
    }
#undef DOT_CHAIN

    // lex-min (d, c) across the 8 slots of this position
    #pragma unroll
    for (int off = 1; off < 8; off <<= 1) {
        const float od = __shfl_xor(bd, off);
        const int   oi = __shfl_xor(bc, off);
        if (od < bd || (od == bd && oi < bc)) { bd = od; bc = oi; }
    }
    if (slot == 0) idx_out[p] = (float)bc;
}

// ---------------------------------------------------------------------------
// k3: gather + straight-through. Block = fixed (n, c), 256 hw4-units.
// Wt column row staged coalesced into LDS (4KB); per-thread code reads are
// LDS scalars. All global reads/writes coalesced. Values bitwise-unchanged.
// ---------------------------------------------------------------------------
__global__ void k3_gather(const float* __restrict__ z, const float* __restrict__ wtf,
                          const float* __restrict__ idxf,
                          float* __restrict__ out0, float* __restrict__ out1) {
    __shared__ float wcol[1024];
    const int tid = threadIdx.x;
    const int b = blockIdx.x;              // 8192 = 32 n x 256 c
    const int c = b & 255, n = b >> 8;
    *(float4*)&wcol[tid * 4] = *(const float4*)&wtf[(size_t)c * 1024 + tid * 4];
    __syncthreads();

    const size_t zo = (((size_t)(n * 256 + c)) << 10) + tid * 4;
    const float4 zv = *(const float4*)&z[zo];
    const float4 iv = *(const float4*)&idxf[n * 1024 + tid * 4];
    float4 qv, st;
    qv.x = wcol[(int)iv.x]; st.x = (qv.x - zv.x) + zv.x;
    qv.y = wcol[(int)iv.y]; st.y = (qv.y - zv.y) + zv.y;
    qv.z = wcol[(int)iv.z]; st.z = (qv.z - zv.z) + zv.z;
    qv.w = wcol[(int)iv.w]; st.w = (qv.w - zv.w) + zv.w;
    *(float4*)&out0[zo] = qv;
    *(float4*)&out1[zo] = st;
}

extern "C" void kernel_launch(void* const* d_in, const int* in_sizes, int n_in,
                              void* d_out, int out_size, void* d_ws, size_t ws_size,
                              hipStream_t stream) {
    const float* z = (const float*)d_in[0];
    const float* wemb = (const float*)d_in[1];
    float* out = (float*)d_out;
    float* out0 = out;                       // quantized (final)
    float* out1 = out + Q_ELEMS;             // straight_through (final)
    float* oidx = out + 2 * Q_ELEMS;         // indices-as-float (final)
    // big scratch inside d_out (all consumed before k3 overwrites):
    unsigned short* zhi = (unsigned short*)out0;                  // 16 MB  [0..4M floats)
    unsigned short* candC = (unsigned short*)(out0 + 4194304);    // 8 MB   [4M..6M floats)
    int* candCnt = (int*)(out0 + 6291456);                        // 128 KB [6M..6.03M)
    unsigned short* whi = (unsigned short*)out1;                  // 512 KB (out1 head)
    // d_ws scratch (~1.05 MB, within proven capacity):
    float* wsq = (float*)d_ws;                // 1024 f32
    float* wtf = (float*)d_ws + 1024;         // 262144 f32 (Wt, exact f32)

    k0t_transpose<<<64, 256, 0, stream>>>(wemb, wtf);
    k0w_pack<<<128, 256, 0, stream>>>(wemb, whi);
    k0z_pack<<<512, 256, 0, stream>>>(z, zhi);
    k1_wsq<<<132, 256, 0, stream>>>(wemb, wsq, candCnt);
    k2s_screen<<<1024, 256, 0, stream>>>(zhi, whi, wsq, candC, candCnt);
    k2r_rescore<<<P_TOTAL / 32, 256, 0, stream>>>(z, wemb, wsq, candC, candCnt, oidx);
    k3_gather<<<8192, 256, 0, stream>>>(z, wtf, oidx, out0, out1);
}